// Round 7
// baseline (160.973 us; speedup 1.0000x reference)
//
#include <hip/hip_runtime.h>

#define GENE_N  200000
#define BATCH   200000
#define EMBED   128
#define BM      32
#define THREADS 512
#define L2E     1.44269504088896340736f

typedef __attribute__((ext_vector_type(8))) short bf16x8;
typedef __attribute__((ext_vector_type(4))) float f32x4;

static __device__ __forceinline__ short f2bf(float f) {
    unsigned u = __builtin_bit_cast(unsigned, f);
    unsigned r = (u + 0x7fffu + ((u >> 16) & 1u)) >> 16;   // RNE
    return (short)(r & 0xffffu);
}
static __device__ __forceinline__ unsigned cvt_pk_bf16(float lo, float hi) {
    unsigned r;
    asm("v_cvt_pk_bf16_f32 %0, %1, %2" : "=v"(r) : "v"(lo), "v"(hi));
    return r;
}

// (512,4) = 2 blocks/CU (128-reg cap). BM=32 + pair-wise tiles:
//  - one barrier per TWO tiles (convoy cost halved vs r6)
//  - XOR-swizzled LDS (row-major [32][128] shorts, col ^= (row&7)<<3):
//    balanced banks on both int2 writes and b128 reads, no pad.
__global__ __launch_bounds__(THREADS, 4)
void hetagg_kernel(const float* __restrict__ gene_feat,
                   const float* __restrict__ cell_feat,
                   const float* __restrict__ gWf, const float* __restrict__ gbf,
                   const float* __restrict__ gWb, const float* __restrict__ gbb,
                   const float* __restrict__ cWf, const float* __restrict__ cbf,
                   const float* __restrict__ cWb, const float* __restrict__ cbb,
                   const int* __restrict__ c_ids, const int* __restrict__ p_ids,
                   const int* __restrict__ n_ids, float* __restrict__ out,
                   int gene_blocks, int cell_blocks)
{
    __shared__ short A_lds[2][2][BM * EMBED];   // [pair parity][tile in pair]

    const int  bid     = blockIdx.x;
    const bool is_gene = (bid < gene_blocks);
    const int  tid     = threadIdx.x;
    const int  wid     = tid >> 6;
    const int  lane    = tid & 63;
    const int  lgrp    = lane >> 4;   // 0..3
    const int  lcol    = lane & 15;   // 0..15
    const int  dir     = wid >> 2;    // 0 fwd, 1 bwd
    const int  jt      = wid & 3;     // 16-wide j block
    const int  j       = jt * 16 + lcol;

    const float* feat = is_gene ? gene_feat : cell_feat;
    const float* W    = is_gene ? (dir ? gWb : gWf) : (dir ? cWb : cWf);
    const float* Bv   = is_gene ? (dir ? gbb : gbf) : (dir ? cbb : cbf);

    // exp2-domain gate scales folded into weights:
    //   a0 = -i*log2e (u=2^a0=e^-i); a1 = 2g*log2e (v=e^{2g}); a2 = -o*log2e (w=e^-o)
    const float gsc[3] = {-L2E, 2.0f * L2E, -L2E};
    const float b0 = -L2E * Bv[j];
    const float b1 = 2.0f * L2E * Bv[128 + j];
    const float b2 = -L2E * Bv[192 + j];

    // B fragments in registers for the whole kernel (pre-scaled)
    bf16x8 bfrag[3][4];
    {
        const int gate_base[3] = {0, 128, 192};
#pragma unroll
        for (int q = 0; q < 3; ++q) {
            const float* wrow = W + (size_t)(gate_base[q] + j) * EMBED;
            const float  sc   = gsc[q];
#pragma unroll
            for (int s = 0; s < 4; ++s) {
                const int k0 = s * 32 + lgrp * 8;
                float4 w0 = *(const float4*)(wrow + k0);
                float4 w1 = *(const float4*)(wrow + k0 + 4);
                bf16x8 b;
                b[0] = f2bf(sc * w0.x); b[1] = f2bf(sc * w0.y);
                b[2] = f2bf(sc * w0.z); b[3] = f2bf(sc * w0.w);
                b[4] = f2bf(sc * w1.x); b[5] = f2bf(sc * w1.y);
                b[6] = f2bf(sc * w1.z); b[7] = f2bf(sc * w1.w);
                bfrag[q][s] = b;
            }
        }
    }

    const int myb    = is_gene ? bid : (bid - gene_blocks);
    const int nb     = is_gene ? gene_blocks : cell_blocks;
    const int ntiles = is_gene ? (BATCH / BM) : (2 * BATCH / BM);
    const int nk     = (ntiles - myb + nb - 1) / nb;   // tiles for this block

    const int r0  = tid >> 5;              // 0..15 (row within half-pass)
    const int cc  = tid & 31;              // float4 col within row
    const int wsw = (r0 & 7) << 3;         // write-side XOR swizzle (shorts)
    const int rsw = (lcol & 7) << 3;       // read-side XOR swizzle (shorts)

#define FETCH_ID(grow) (is_gene ? c_ids[(grow)] \
                       : ((grow) < BATCH ? p_ids[(grow)] - GENE_N \
                                         : n_ids[(grow) - BATCH] - GENE_N))

    // ---- prologue: rows(0)->rvA, rows(1)->rvB, ids(2)->idA, ids(3)->idB
    float4 rvA[2], rvB[2];
    int    idA[2], idB[2];
    {
        int id0[2], id1[2];
#pragma unroll
        for (int p = 0; p < 2; ++p) id0[p] = FETCH_ID(myb * BM + r0 + p * 16);
#pragma unroll
        for (int p = 0; p < 2; ++p)
            rvA[p] = ((const float4*)(feat + (size_t)id0[p] * EMBED))[cc];
        if (nk > 1) {
#pragma unroll
            for (int p = 0; p < 2; ++p) id1[p] = FETCH_ID((myb + nb) * BM + r0 + p * 16);
#pragma unroll
            for (int p = 0; p < 2; ++p)
                rvB[p] = ((const float4*)(feat + (size_t)id1[p] * EMBED))[cc];
        }
        if (nk > 2) {
#pragma unroll
            for (int p = 0; p < 2; ++p) idA[p] = FETCH_ID((myb + 2 * nb) * BM + r0 + p * 16);
        }
        if (nk > 3) {
#pragma unroll
            for (int p = 0; p < 2; ++p) idB[p] = FETCH_ID((myb + 3 * nb) * BM + r0 + p * 16);
        }
    }

#define STAGE(RV, BUF)                                                          \
    {                                                                           \
        _Pragma("unroll")                                                       \
        for (int p = 0; p < 2; ++p) {                                           \
            int2 sv;                                                            \
            sv.x = (int)cvt_pk_bf16(RV[p].x, RV[p].y);                          \
            sv.y = (int)cvt_pk_bf16(RV[p].z, RV[p].w);                          \
            *(int2*)&(BUF)[(r0 + p * 16) * EMBED + ((cc * 4) ^ wsw)] = sv;      \
        }                                                                       \
    }

#define TILE_COMPUTE(BASE, BUF)                                                 \
    {                                                                           \
        _Pragma("unroll")                                                       \
        for (int mt = 0; mt < 2; ++mt) {                                        \
            f32x4 acc0 = {b0, b0, b0, b0};                                      \
            f32x4 acc1 = {b1, b1, b1, b1};                                      \
            f32x4 acc2 = {b2, b2, b2, b2};                                      \
            const int m_ = mt * 16 + lcol;                                      \
            _Pragma("unroll")                                                   \
            for (int s = 0; s < 4; ++s) {                                       \
                bf16x8 a = *(const bf16x8*)&(BUF)[m_ * EMBED + ((s * 32 + lgrp * 8) ^ rsw)]; \
                acc0 = __builtin_amdgcn_mfma_f32_16x16x32_bf16(a, bfrag[0][s], acc0, 0, 0, 0); \
                acc1 = __builtin_amdgcn_mfma_f32_16x16x32_bf16(a, bfrag[1][s], acc1, 0, 0, 0); \
                acc2 = __builtin_amdgcn_mfma_f32_16x16x32_bf16(a, bfrag[2][s], acc2, 0, 0, 0); \
            }                                                                   \
            _Pragma("unroll")                                                   \
            for (int r = 0; r < 4; ++r) {                                       \
                const float a0 = acc0[r];                                       \
                const float a1 = fminf(acc1[r], 80.0f);                         \
                const float a2 = acc2[r];                                       \
                const float u  = __builtin_amdgcn_exp2f(a0);                    \
                const float v  = __builtin_amdgcn_exp2f(a1);                    \
                const float w  = __builtin_amdgcn_exp2f(a2);                    \
                const float tprod = (1.0f + u) * (v + 1.0f);                    \
                const float c  = (v - 1.0f) * __builtin_amdgcn_rcpf(tprod);     \
                const float c2 = c * c;                                         \
                const float num = c * (15.0f + c2);                             \
                const float den = (15.0f + 6.0f * c2) * (1.0f + w);             \
                const float h   = num * __builtin_amdgcn_rcpf(den);             \
                const int row   = (BASE) + mt * 16 + lgrp * 4 + r;              \
                const size_t orow = (size_t)(is_gene ? row : (BATCH + row));    \
                out[orow * 128 + dir * 64 + j] = h;                             \
            }                                                                   \
        }                                                                       \
    }

    int pp = 0;   // pair parity
    int k  = 0;
    for (; k + 1 < nk; k += 2, pp ^= 1) {
        short* buf0 = A_lds[pp][0];
        short* buf1 = A_lds[pp][1];

        // stage both tiles of the pair
        STAGE(rvA, buf0);
        STAGE(rvB, buf1);
        asm volatile("s_waitcnt lgkmcnt(0)" ::: "memory");
        __builtin_amdgcn_s_barrier();
        // 4-buffer discipline: writes to parity pp here happen one full
        // pair-iteration after the last reads of pp (which precede the
        // previous iteration's barrier in every wave's program order).

        // issue next pair's gathers (land during ~2 tiles of compute)
        if (k + 2 < nk) {
#pragma unroll
            for (int p = 0; p < 2; ++p)
                rvA[p] = ((const float4*)(feat + (size_t)idA[p] * EMBED))[cc];
        }
        if (k + 3 < nk) {
#pragma unroll
            for (int p = 0; p < 2; ++p)
                rvB[p] = ((const float4*)(feat + (size_t)idB[p] * EMBED))[cc];
        }
        if (k + 4 < nk) {
            const int t4 = (myb + (k + 4) * nb) * BM;
#pragma unroll
            for (int p = 0; p < 2; ++p) idA[p] = FETCH_ID(t4 + r0 + p * 16);
        }
        if (k + 5 < nk) {
            const int t5 = (myb + (k + 5) * nb) * BM;
#pragma unroll
            for (int p = 0; p < 2; ++p) idB[p] = FETCH_ID(t5 + r0 + p * 16);
        }

        TILE_COMPUTE((myb + k * nb) * BM, buf0);
        TILE_COMPUTE((myb + (k + 1) * nb) * BM, buf1);
    }
    if (k < nk) {   // odd tail
        short* buf0 = A_lds[pp][0];
        STAGE(rvA, buf0);
        asm volatile("s_waitcnt lgkmcnt(0)" ::: "memory");
        __builtin_amdgcn_s_barrier();
        TILE_COMPUTE((myb + k * nb) * BM, buf0);
    }

#undef TILE_COMPUTE
#undef STAGE
#undef FETCH_ID
}

extern "C" void kernel_launch(void* const* d_in, const int* in_sizes, int n_in,
                              void* d_out, int out_size, void* d_ws, size_t ws_size,
                              hipStream_t stream)
{
    const float* gene_feat = (const float*)d_in[0];
    const float* cell_feat = (const float*)d_in[1];
    const float* gWf = (const float*)d_in[2];
    const float* gbf = (const float*)d_in[3];
    const float* gWb = (const float*)d_in[4];
    const float* gbb = (const float*)d_in[5];
    const float* cWf = (const float*)d_in[6];
    const float* cbf = (const float*)d_in[7];
    const float* cWb = (const float*)d_in[8];
    const float* cbb = (const float*)d_in[9];
    const int* c_ids = (const int*)d_in[10];
    const int* p_ids = (const int*)d_in[11];
    const int* n_ids = (const int*)d_in[12];
    float* out = (float*)d_out;

    const int gene_blocks = 171;   // 6250 tiles of 32 rows -> 36-37 tiles/block
    const int cell_blocks = 341;   // 12500 tiles           -> 36-37 tiles/block
    dim3 grid(gene_blocks + cell_blocks);   // 512 = 2 blocks/CU, one round
    dim3 block(THREADS);
    hipLaunchKernelGGL(hetagg_kernel, grid, block, 0, stream,
                       gene_feat, cell_feat, gWf, gbf, gWb, gbb,
                       cWf, cbf, cWb, cbb, c_ids, p_ids, n_ids, out,
                       gene_blocks, cell_blocks);
}